// Round 2
// baseline (449.441 us; speedup 1.0000x reference)
//
#include <hip/hip_runtime.h>
#include <cstdint>
#include <cstddef>

#define BETA 5.5f
#define ALPHA 0.5f

constexpr int D   = 512;     // feature dim
constexpr int NB  = 4096;    // queries
constexpr int NK  = 16384;   // keys
constexpr int BQ  = 64;      // query tile per block
constexpr int BN  = 64;      // key chunk
constexpr int NSPLIT = 4;
constexpr int NRANGE = NK / NSPLIT;   // 4096
constexpr int CHUNKS = NRANGE / BN;   // 64
constexpr int KROW = D + 8;           // padded LDS row (bf16) for norm_k transpose
constexpr int PROW = BN + 8;          // padded P row: 72

typedef __attribute__((ext_vector_type(8)))  short    short8;
typedef __attribute__((ext_vector_type(4)))  float    floatx4;
typedef __attribute__((ext_vector_type(4)))  uint32_t uint4v;
typedef __attribute__((ext_vector_type(2)))  uint32_t uint2v;

__device__ inline uint32_t f2bf1(float f) {
  union { float f; uint32_t u; } v; v.f = f;
  return (v.u + 0x7FFFu + ((v.u >> 16) & 1u)) >> 16;   // RNE
}
__device__ inline uint32_t pack2(float a, float b) {
  return f2bf1(a) | (f2bf1(b) << 16);
}

// raw barrier: lgkm drain (P_lds visibility) but NO vmcnt drain — global
// register prefetches (K frags, ktf) stay in flight across the barrier.
// Sound because no global_load_lds is used: the only cross-wave medium is
// P_lds (ds_write -> lgkmcnt(0) -> s_barrier -> ds_read).
__device__ inline void region_barrier() {
  asm volatile("s_waitcnt lgkmcnt(0)\n\ts_barrier" ::: "memory");
}

// ---------------- normalize Q -> Qn (bf16), and init out = Q ----------------
__global__ void norm_q_kernel(const float* __restrict__ q,
                              float* __restrict__ out,
                              unsigned short* __restrict__ Qn) {
  const int wave = threadIdx.x >> 6, lane = threadIdx.x & 63;
  const int row = blockIdx.x * 4 + wave;
  const float4* qr = (const float4*)(q + (size_t)row * D);
  float4 a = qr[lane * 2];
  float4 b = qr[lane * 2 + 1];
  float ss = a.x*a.x + a.y*a.y + a.z*a.z + a.w*a.w
           + b.x*b.x + b.y*b.y + b.z*b.z + b.w*b.w;
#pragma unroll
  for (int m = 32; m >= 1; m >>= 1) ss += __shfl_xor(ss, m, 64);
  const float sc = 1.0f / fmaxf(sqrtf(ss), 1e-12f);
  float4* orow = (float4*)(out + (size_t)row * D);
  orow[lane * 2]     = a;
  orow[lane * 2 + 1] = b;
  uint4v w;
  w.x = pack2(a.x*sc, a.y*sc); w.y = pack2(a.z*sc, a.w*sc);
  w.z = pack2(b.x*sc, b.y*sc); w.w = pack2(b.z*sc, b.w*sc);
  *(uint4v*)(Qn + (size_t)row * D + lane * 8) = w;
}

// ------ normalize K -> Kn (bf16 row-major) + KnT (bf16 transposed) ----------
__global__ void norm_k_kernel(const float* __restrict__ k,
                              unsigned short* __restrict__ Kn,
                              unsigned short* __restrict__ KnT) {
  __shared__ unsigned short tile[64 * KROW];
  const int wave = threadIdx.x >> 6, lane = threadIdx.x & 63;
  const int n0 = blockIdx.x * 64;
#pragma unroll
  for (int i = 0; i < 4; ++i) {
    const int rl = wave * 4 + i;
    const int n  = n0 + rl;
    const float4* kr = (const float4*)(k + (size_t)n * D);
    float4 a = kr[lane * 2], b = kr[lane * 2 + 1];
    float ss = a.x*a.x + a.y*a.y + a.z*a.z + a.w*a.w
             + b.x*b.x + b.y*b.y + b.z*b.z + b.w*b.w;
#pragma unroll
    for (int m = 32; m >= 1; m >>= 1) ss += __shfl_xor(ss, m, 64);
    const float sc = 1.0f / fmaxf(sqrtf(ss), 1e-12f);
    uint4v w;
    w.x = pack2(a.x*sc, a.y*sc); w.y = pack2(a.z*sc, a.w*sc);
    w.z = pack2(b.x*sc, b.y*sc); w.w = pack2(b.z*sc, b.w*sc);
    *(uint4v*)(Kn + (size_t)n * D + lane * 8) = w;
    *(uint4v*)&tile[rl * KROW + lane * 8]     = w;
  }
  __syncthreads();
  const int dsub = threadIdx.x >> 3;        // 0..127
  const int nl   = (threadIdx.x & 7) * 8;   // 0..56
#pragma unroll
  for (int iter = 0; iter < 4; ++iter) {
    const int d = iter * 128 + dsub;
    uint4v w;
    w.x = (uint32_t)tile[(nl+0)*KROW + d] | ((uint32_t)tile[(nl+1)*KROW + d] << 16);
    w.y = (uint32_t)tile[(nl+2)*KROW + d] | ((uint32_t)tile[(nl+3)*KROW + d] << 16);
    w.z = (uint32_t)tile[(nl+4)*KROW + d] | ((uint32_t)tile[(nl+5)*KROW + d] << 16);
    w.w = (uint32_t)tile[(nl+6)*KROW + d] | ((uint32_t)tile[(nl+7)*KROW + d] << 16);
    *(uint4v*)(KnT + (size_t)d * NK + n0 + nl) = w;
  }
}

// ---------------- fused: S = Qn Kn^T chunk, P = exp, O += P Kn --------------
// v3: NO K_lds staging, NO __syncthreads. S-waves (0-3) load K fragments
// straight from global into registers (imm-offset dwordx4, 2-group software
// pipeline); O-waves (4-7) unchanged GEMM2 from registers. Only cross-wave
// data is P (double-buffered LDS, 18 KB) -> one raw s_barrier + lgkmcnt(0)
// per region, with all global prefetches (K group-0 of next chunk, ktf of
// next chunk) IN FLIGHT across the barrier (counted-vmcnt by the compiler).
// This removes the per-region vmcnt(0) drain + phase convoy that capped the
// 2-barrier structure at ~28% of the MFMA floor (matches learn_hip m233).
__global__ __launch_bounds__(512, 2) void fused_kernel(
    const unsigned short* __restrict__ Qn,
    const unsigned short* __restrict__ Kn,
    const unsigned short* __restrict__ KnT,
    float* __restrict__ out) {
  __shared__ unsigned short P_lds[2][BQ * PROW];   // 2 x 9.2 KB only

  const int tid  = threadIdx.x;
  const int wave = tid >> 6, lane = tid & 63;
  const int l15  = lane & 15, quad = lane >> 4;
  const int nsplit = blockIdx.x & (NSPLIT - 1);
  const int qtile  = blockIdx.x >> 2;           // 0..63
  const int q0     = qtile * BQ;
  const int nbase  = nsplit * NRANGE;

  if (wave < 4) {
    // ================= S-producer: GEMM1 + exp -> P_lds ===================
    const int qh = wave & 1, nh = wave >> 1;
    // Q B-fragments: 32 q-cols x all 512 k -> 128 VGPR (persistent)
    short8 qf[2][16];
    {
      const unsigned short* qrow0 = Qn + (size_t)(q0 + qh * 32 + l15) * D + quad * 8;
#pragma unroll
      for (int qt = 0; qt < 2; ++qt)
#pragma unroll
        for (int kb = 0; kb < 16; ++kb)
          qf[qt][kb] = *(const short8*)(qrow0 + (size_t)qt * 16 * D + kb * 32);
    }

    // per-lane K row bases (rows nh*32+l15 and +16); chunk advances by c*64*D
    const unsigned short* pK0 = Kn + (size_t)(nbase + nh * 32 + l15) * D + quad * 8;
    const unsigned short* pK1 = pK0 + (size_t)16 * D;

    short8 kfA[8], kfB[8];   // two 4-kb groups in flight (64 VGPR)
    floatx4 sacc[2][2];

    auto ldK = [&](short8* kf, int c, int g) {
      const size_t cb = (size_t)c * 64 * D;
#pragma unroll
      for (int i = 0; i < 4; ++i) {
        kf[2*i]   = *(const short8*)(pK0 + cb + (g*4 + i) * 32);
        kf[2*i+1] = *(const short8*)(pK1 + cb + (g*4 + i) * 32);
      }
    };
    auto mfma_g = [&](const short8* kf, int g) {
      __builtin_amdgcn_s_setprio(1);
#pragma unroll
      for (int i = 0; i < 4; ++i) {
        const int kb = g*4 + i;
        sacc[0][0] = __builtin_amdgcn_mfma_f32_16x16x32_bf16(kf[2*i],   qf[0][kb], sacc[0][0], 0, 0, 0);
        sacc[0][1] = __builtin_amdgcn_mfma_f32_16x16x32_bf16(kf[2*i],   qf[1][kb], sacc[0][1], 0, 0, 0);
        sacc[1][0] = __builtin_amdgcn_mfma_f32_16x16x32_bf16(kf[2*i+1], qf[0][kb], sacc[1][0], 0, 0, 0);
        sacc[1][1] = __builtin_amdgcn_mfma_f32_16x16x32_bf16(kf[2*i+1], qf[1][kb], sacc[1][1], 0, 0, 0);
      }
      __builtin_amdgcn_s_setprio(0);
    };

    ldK(kfA, 0, 0);                        // prologue: group 0 of chunk 0
#pragma unroll 1
    for (int c = 0; c < CHUNKS; ++c) {
#pragma unroll
      for (int nt = 0; nt < 2; ++nt)
#pragma unroll
        for (int qt = 0; qt < 2; ++qt) sacc[nt][qt] = (floatx4){0.f, 0.f, 0.f, 0.f};

      ldK(kfB, c, 1);  mfma_g(kfA, 0);
      ldK(kfA, c, 2);  mfma_g(kfB, 1);
      ldK(kfB, c, 3);  mfma_g(kfA, 2);
      if (c + 1 < CHUNKS) ldK(kfA, c + 1, 0);   // cross-barrier prefetch
      mfma_g(kfB, 3);

      // exp + pack + P write (buffer c&1)
      const int pb = c & 1;
#pragma unroll
      for (int qt = 0; qt < 2; ++qt)
#pragma unroll
        for (int nt = 0; nt < 2; ++nt) {
          const floatx4 s = sacc[nt][qt];
          uint2v w;
          w.x = pack2(__expf(BETA * (s[0] - 1.f)), __expf(BETA * (s[1] - 1.f)));
          w.y = pack2(__expf(BETA * (s[2] - 1.f)), __expf(BETA * (s[3] - 1.f)));
          *(uint2v*)&P_lds[pb][(qh*32 + qt*16 + l15) * PROW + nh*32 + nt*16 + quad*4] = w;
        }
      region_barrier();                    // barrier #c (CHUNKS total)
    }
    // S done: O-waves execute no further barriers either (counts match).
  } else {
    // ================= O-consumer: GEMM2 + epilogue =======================
    const int w4 = wave - 4;               // d-slice of 128
    floatx4 oacc[4][8] = {};               // 64q x 128d (128 VGPR)
    short8 kt0[8], kt1[8];                 // KnT frags, 64 VGPR, WAR-recycled
    const unsigned short* ktb = KnT + (size_t)(w4 * 128 + l15) * NK + nbase + quad * 8;

    auto ldKT = [&](short8* kt, int c, int kb2) {
#pragma unroll
      for (int td = 0; td < 8; ++td)
        kt[td] = *(const short8*)(ktb + (size_t)td * 16 * NK + c * 64 + kb2 * 32);
    };
    auto g2 = [&](int pb, int kb2, const short8* kt) {
      short8 pf[4];
#pragma unroll
      for (int tr = 0; tr < 4; ++tr)
        pf[tr] = *(const short8*)&P_lds[pb][(tr*16 + l15) * PROW + kb2*32 + quad*8];
      __builtin_amdgcn_s_setprio(1);
#pragma unroll
      for (int td = 0; td < 8; ++td)
#pragma unroll
        for (int tr = 0; tr < 4; ++tr)
          oacc[tr][td] = __builtin_amdgcn_mfma_f32_16x16x32_bf16(
              pf[tr], kt[td], oacc[tr][td], 0, 0, 0);
      __builtin_amdgcn_s_setprio(0);
    };

    ldKT(kt0, 0, 0); ldKT(kt1, 0, 1);      // ktf for chunk 0
    region_barrier();                      // barrier #0 (P(0) now visible)

#pragma unroll 1
    for (int c = 1; c < CHUNKS; ++c) {
      const int pb = (c - 1) & 1;
      g2(pb, 0, kt0);                      // consume chunk c-1, kb2=0
      ldKT(kt0, c, 0);                     // WAR reload -> chunk c (in flight across barrier)
      g2(pb, 1, kt1);
      ldKT(kt1, c, 1);
      region_barrier();                    // barrier #c
    }
    // final consume (no barrier needed; S already exited after its last one)
    g2((CHUNKS - 1) & 1, 0, kt0);
    g2((CHUNKS - 1) & 1, 1, kt1);

    // ---- epilogue: out += ALPHA * O (out pre-init to Q) ----
    const int colbase = w4 * 128 + l15;
#pragma unroll
    for (int tr = 0; tr < 4; ++tr)
#pragma unroll
      for (int td = 0; td < 8; ++td)
#pragma unroll
      for (int r = 0; r < 4; ++r)
        atomicAdd(out + (size_t)(q0 + tr*16 + quad*4 + r) * D + colbase + td*16,
                  ALPHA * oacc[tr][td][r]);
  }
}

extern "C" void kernel_launch(void* const* d_in, const int* in_sizes, int n_in,
                              void* d_out, int out_size, void* d_ws, size_t ws_size,
                              hipStream_t stream) {
  (void)in_sizes; (void)n_in; (void)out_size; (void)ws_size;
  const float* q = (const float*)d_in[0];
  const float* k = (const float*)d_in[1];
  float* out = (float*)d_out;
  unsigned short* Qn  = (unsigned short*)d_ws;          //  4 MB
  unsigned short* Kn  = Qn + (size_t)NB * D;            // 16 MB
  unsigned short* KnT = Kn + (size_t)NK * D;            // 16 MB  (total 36 MB)

  hipLaunchKernelGGL(norm_q_kernel, dim3(NB / 4),  dim3(256),  0, stream, q, out, Qn);
  hipLaunchKernelGGL(norm_k_kernel, dim3(NK / 64), dim3(1024), 0, stream, k, Kn, KnT);
  hipLaunchKernelGGL(fused_kernel, dim3((NB / BQ) * NSPLIT), dim3(512), 0, stream,
                     Qn, Kn, KnT, out);
}

// Round 3
// 334.713 us; speedup vs baseline: 1.3428x; 1.3428x over previous
//
#include <hip/hip_runtime.h>
#include <cstdint>
#include <cstddef>

#define BETA 5.5f
#define ALPHA 0.5f

constexpr int D   = 512;     // feature dim
constexpr int NB  = 4096;    // queries
constexpr int NK  = 16384;   // keys
constexpr int BQ  = 64;      // query tile per block
constexpr int BN  = 64;      // key chunk
constexpr int NSPLIT = 4;
constexpr int NRANGE = NK / NSPLIT;   // 4096
constexpr int CHUNKS = NRANGE / BN;   // 64
constexpr int KROW = D + 8;           // padded LDS row (bf16), 1040 B
constexpr int PROW = BN + 8;          // padded P row: 72

typedef __attribute__((ext_vector_type(8)))  short    short8;
typedef __attribute__((ext_vector_type(4)))  float    floatx4;
typedef __attribute__((ext_vector_type(4)))  uint32_t uint4v;
typedef __attribute__((ext_vector_type(2)))  uint32_t uint2v;

__device__ inline uint32_t f2bf1(float f) {
  union { float f; uint32_t u; } v; v.f = f;
  return (v.u + 0x7FFFu + ((v.u >> 16) & 1u)) >> 16;   // RNE
}
__device__ inline uint32_t pack2(float a, float b) {
  return f2bf1(a) | (f2bf1(b) << 16);
}

__device__ inline void load_lds16(const void* g, void* l) {
  __builtin_amdgcn_global_load_lds(
      (const __attribute__((address_space(1))) uint32_t*)g,
      (__attribute__((address_space(3))) uint32_t*)l, 16, 0, 0);
}

// ---------------- normalize Q -> Qn (bf16), and init out = Q ----------------
__global__ void norm_q_kernel(const float* __restrict__ q,
                              float* __restrict__ out,
                              unsigned short* __restrict__ Qn) {
  const int wave = threadIdx.x >> 6, lane = threadIdx.x & 63;
  const int row = blockIdx.x * 4 + wave;
  const float4* qr = (const float4*)(q + (size_t)row * D);
  float4 a = qr[lane * 2];
  float4 b = qr[lane * 2 + 1];
  float ss = a.x*a.x + a.y*a.y + a.z*a.z + a.w*a.w
           + b.x*b.x + b.y*b.y + b.z*b.z + b.w*b.w;
#pragma unroll
  for (int m = 32; m >= 1; m >>= 1) ss += __shfl_xor(ss, m, 64);
  const float sc = 1.0f / fmaxf(sqrtf(ss), 1e-12f);
  float4* orow = (float4*)(out + (size_t)row * D);
  orow[lane * 2]     = a;
  orow[lane * 2 + 1] = b;
  uint4v w;
  w.x = pack2(a.x*sc, a.y*sc); w.y = pack2(a.z*sc, a.w*sc);
  w.z = pack2(b.x*sc, b.y*sc); w.w = pack2(b.z*sc, b.w*sc);
  *(uint4v*)(Qn + (size_t)row * D + lane * 8) = w;
}

// ------ normalize K -> Kn (bf16 row-major) + KnT (bf16 transposed) ----------
__global__ void norm_k_kernel(const float* __restrict__ k,
                              unsigned short* __restrict__ Kn,
                              unsigned short* __restrict__ KnT) {
  __shared__ unsigned short tile[64 * KROW];
  const int wave = threadIdx.x >> 6, lane = threadIdx.x & 63;
  const int n0 = blockIdx.x * 64;
#pragma unroll
  for (int i = 0; i < 4; ++i) {
    const int rl = wave * 4 + i;
    const int n  = n0 + rl;
    const float4* kr = (const float4*)(k + (size_t)n * D);
    float4 a = kr[lane * 2], b = kr[lane * 2 + 1];
    float ss = a.x*a.x + a.y*a.y + a.z*a.z + a.w*a.w
             + b.x*b.x + b.y*b.y + b.z*b.z + b.w*b.w;
#pragma unroll
    for (int m = 32; m >= 1; m >>= 1) ss += __shfl_xor(ss, m, 64);
    const float sc = 1.0f / fmaxf(sqrtf(ss), 1e-12f);
    uint4v w;
    w.x = pack2(a.x*sc, a.y*sc); w.y = pack2(a.z*sc, a.w*sc);
    w.z = pack2(b.x*sc, b.y*sc); w.w = pack2(b.z*sc, b.w*sc);
    *(uint4v*)(Kn + (size_t)n * D + lane * 8) = w;
    *(uint4v*)&tile[rl * KROW + lane * 8]     = w;
  }
  __syncthreads();
  const int dsub = threadIdx.x >> 3;        // 0..127
  const int nl   = (threadIdx.x & 7) * 8;   // 0..56
#pragma unroll
  for (int iter = 0; iter < 4; ++iter) {
    const int d = iter * 128 + dsub;
    uint4v w;
    w.x = (uint32_t)tile[(nl+0)*KROW + d] | ((uint32_t)tile[(nl+1)*KROW + d] << 16);
    w.y = (uint32_t)tile[(nl+2)*KROW + d] | ((uint32_t)tile[(nl+3)*KROW + d] << 16);
    w.z = (uint32_t)tile[(nl+4)*KROW + d] | ((uint32_t)tile[(nl+5)*KROW + d] << 16);
    w.w = (uint32_t)tile[(nl+6)*KROW + d] | ((uint32_t)tile[(nl+7)*KROW + d] << 16);
    *(uint4v*)(KnT + (size_t)d * NK + n0 + nl) = w;
  }
}

// ---------------- fused: S = Qn Kn^T chunk, P = exp, O += P Kn --------------
// v4: R0 data layout + ops, re-scheduled as a 6-phase-per-chunk interleave
// (learn_hip T3+T4+T5): each phase = {issue ds/vm loads; s_barrier;
// lgkmcnt(0); setprio(1); MFMA cluster; setprio(0); s_barrier}. vmcnt is
// counted ONCE per region (vmcnt(8), keeping next-chunk ktf loads in
// flight) — never drained to 0 in the loop. This replaces __syncthreads'
// vmcnt(0)-drain convoy that capped R0/R1 at ~23% MfmaUtil (m233 plateau).
__global__ __launch_bounds__(512, 2) void fused_kernel(
    const unsigned short* __restrict__ Qn,
    const unsigned short* __restrict__ Kn,
    const unsigned short* __restrict__ KnT,
    float* __restrict__ out) {
  __shared__ unsigned short K_lds[2][BN * KROW];   // 2 x 66.5 KB
  __shared__ unsigned short P_lds[2][BQ * PROW];   // 2 x 9.2 KB  (151.5 KB)

  const int tid  = threadIdx.x;
  const int wave = tid >> 6, lane = tid & 63;
  const int l15  = lane & 15, quad = lane >> 4;
  const int nsplit = blockIdx.x & (NSPLIT - 1);
  const int qtile  = blockIdx.x >> 2;           // 0..63
  const int q0     = qtile * BQ;
  const int nbase  = nsplit * NRANGE;
  const int tb = wave & 3, nh = wave >> 2;

  // Q B-fragments in registers: wave's 16-col b-tile, all 512 d (64 VGPR)
  short8 qf[16];
  {
    const unsigned short* qrow = Qn + (size_t)(q0 + tb * 16 + l15) * D + quad * 8;
#pragma unroll
    for (int kb = 0; kb < 16; ++kb) qf[kb] = *(const short8*)(qrow + kb * 32);
  }

  floatx4 oacc[4][4] = {};   // wave's 64x64 O slice (AGPR)
  short8 ktf[2][4];          // KnT B-frags (32 VGPR)

  const unsigned short* ktrow = KnT + (size_t)(wave*64 + l15) * NK + nbase + quad*8;

  // ---- helpers ---------------------------------------------------------
  auto stage = [&](int ch, int buf) {
#pragma unroll
    for (int i = 0; i < 8; ++i) {
      const int row = wave * 8 + i;
      load_lds16(Kn + (size_t)(nbase + ch*BN + row) * D + lane * 8,
                 &K_lds[buf][row * KROW]);
    }
  };
  auto ktf_load_h = [&](int ch, int kb2) {
#pragma unroll
    for (int td = 0; td < 4; ++td)
      ktf[kb2][td] = *(const short8*)(ktrow + (size_t)td*16*NK + ch*BN + kb2*32);
  };
  auto pf_read = [&](int pbuf, int kb2, short8* pf) {
#pragma unroll
    for (int tr = 0; tr < 4; ++tr)
      pf[tr] = *(const short8*)&P_lds[pbuf][(tr*16 + l15) * PROW + kb2*32 + quad*8];
  };
  auto gemm2_mfma = [&](const short8* pf, const short8* kt) {
#pragma unroll
    for (int td = 0; td < 4; ++td)
#pragma unroll
      for (int tr = 0; tr < 4; ++tr)
        oacc[tr][td] = __builtin_amdgcn_mfma_f32_16x16x32_bf16(
            pf[tr], kt[td], oacc[tr][td], 0, 0, 0);
  };
  auto a_read4 = [&](int buf, int kb0, short8* af) {
#pragma unroll
    for (int i = 0; i < 4; ++i) {
      af[2*i]   = *(const short8*)&K_lds[buf][(nh*32 +      l15) * KROW + (kb0+i)*32 + quad*8];
      af[2*i+1] = *(const short8*)&K_lds[buf][(nh*32 + 16 + l15) * KROW + (kb0+i)*32 + quad*8];
    }
  };
  auto gemm1_mfma4 = [&](const short8* af, int kb0, floatx4& s0, floatx4& s1) {
#pragma unroll
    for (int i = 0; i < 4; ++i) {
      s0 = __builtin_amdgcn_mfma_f32_16x16x32_bf16(af[2*i],   qf[kb0+i], s0, 0, 0, 0);
      s1 = __builtin_amdgcn_mfma_f32_16x16x32_bf16(af[2*i+1], qf[kb0+i], s1, 0, 0, 0);
    }
  };
  auto exp_pw = [&](int buf, const floatx4& s0, const floatx4& s1) {
    const int prow = (tb * 16 + l15) * PROW;
    uint2v w0, w1;
    w0.x = pack2(__expf(BETA * (s0[0] - 1.f)), __expf(BETA * (s0[1] - 1.f)));
    w0.y = pack2(__expf(BETA * (s0[2] - 1.f)), __expf(BETA * (s0[3] - 1.f)));
    w1.x = pack2(__expf(BETA * (s1[0] - 1.f)), __expf(BETA * (s1[1] - 1.f)));
    w1.y = pack2(__expf(BETA * (s1[2] - 1.f)), __expf(BETA * (s1[3] - 1.f)));
    *(uint2v*)&P_lds[buf][prow + (nh*2 + 0) * 16 + quad * 4] = w0;
    *(uint2v*)&P_lds[buf][prow + (nh*2 + 1) * 16 + quad * 4] = w1;
  };
  auto ph_begin = [&]() {
    asm volatile("s_barrier" ::: "memory");
    asm volatile("s_waitcnt lgkmcnt(0)" ::: "memory");
    __builtin_amdgcn_sched_barrier(0);
    __builtin_amdgcn_s_setprio(1);
  };
  auto ph_end = [&]() {
    __builtin_amdgcn_s_setprio(0);
    __builtin_amdgcn_sched_barrier(0);
    asm volatile("s_barrier" ::: "memory");
  };
  // ----------------------------------------------------------------------

  // prologue: stage(0) + ktf(0); wait stage(0); {stage(1); GEMM1(0); P(0)}
  stage(0, 0);
  ktf_load_h(0, 0); ktf_load_h(0, 1);
  asm volatile("s_waitcnt vmcnt(8)" ::: "memory");   // stage(0) done, ktf in flight
  asm volatile("s_barrier" ::: "memory");
  {
    stage(1, 1);
    floatx4 s0 = {0.f,0.f,0.f,0.f}, s1 = {0.f,0.f,0.f,0.f};
    short8 af[8];
#pragma unroll
    for (int g = 0; g < 4; ++g) {
      a_read4(0, g*4, af);
      gemm1_mfma4(af, g*4, s0, s1);
    }
    exp_pw(0, s0, s1);
  }
  asm volatile("s_waitcnt vmcnt(0) lgkmcnt(0)" ::: "memory");  // stage(1)+P(0) done
  asm volatile("s_barrier" ::: "memory");

  // steady state: region c = 6 phases. gemm2 consumes chunk c (P_lds[cur],
  // ktf), gemm1 computes chunk c+1 (K_lds[nxt]) -> P_lds[nxt]; stage c+2.
#pragma unroll 1
  for (int c = 0; c + 2 < CHUNKS; ++c) {
    const int cur = c & 1, nxt = cur ^ 1;
    floatx4 s0 = {0.f,0.f,0.f,0.f}, s1 = {0.f,0.f,0.f,0.f};
    short8 pf[4], af[8];
    // A: stage(c+2) + P reads kb2=0 -> gemm2 half0 (ktf[0] = chunk c)
    stage(c + 2, cur);
    pf_read(cur, 0, pf);
    ph_begin(); gemm2_mfma(pf, ktf[0]); ph_end();
    // B1: gemm1 kb0-3
    a_read4(nxt, 0, af);
    ph_begin(); gemm1_mfma4(af, 0, s0, s1); ph_end();
    // B2: gemm1 kb4-7
    a_read4(nxt, 4, af);
    ph_begin(); gemm1_mfma4(af, 4, s0, s1); ph_end();
    // C: P reads kb2=1 + ktf(c+1) half0 -> gemm2 half1 (ktf[1] = chunk c)
    pf_read(cur, 1, pf);
    ktf_load_h(c + 1, 0);
    ph_begin(); gemm2_mfma(pf, ktf[1]); ph_end();
    // D1: gemm1 kb8-11 + ktf(c+1) half1
    a_read4(nxt, 8, af);
    ktf_load_h(c + 1, 1);
    ph_begin(); gemm1_mfma4(af, 8, s0, s1); ph_end();
    // D2: gemm1 kb12-15 -> exp -> P(c+1); region-end counted barrier
    a_read4(nxt, 12, af);
    asm volatile("s_barrier" ::: "memory");
    asm volatile("s_waitcnt lgkmcnt(0)" ::: "memory");
    __builtin_amdgcn_sched_barrier(0);
    __builtin_amdgcn_s_setprio(1);
    gemm1_mfma4(af, 12, s0, s1);
    __builtin_amdgcn_s_setprio(0);
    __builtin_amdgcn_sched_barrier(0);
    exp_pw(nxt, s0, s1);
    // stage(c+2) done (issued a full region ago); ktf(c+1) [8] stay in flight
    asm volatile("s_waitcnt vmcnt(8) lgkmcnt(0)" ::: "memory");
    asm volatile("s_barrier" ::: "memory");
  }
  // tail A: region CHUNKS-2 (no staging): gemm2(CHUNKS-2) + gemm1(CHUNKS-1)
  {
    const int c = CHUNKS - 2, cur = c & 1, nxt = cur ^ 1;
    floatx4 s0 = {0.f,0.f,0.f,0.f}, s1 = {0.f,0.f,0.f,0.f};
    short8 pf[4], af[8];
    pf_read(cur, 0, pf);
    ph_begin(); gemm2_mfma(pf, ktf[0]); ph_end();
    a_read4(nxt, 0, af);
    ph_begin(); gemm1_mfma4(af, 0, s0, s1); ph_end();
    a_read4(nxt, 4, af);
    ph_begin(); gemm1_mfma4(af, 4, s0, s1); ph_end();
    pf_read(cur, 1, pf);
    ktf_load_h(CHUNKS - 1, 0);
    ph_begin(); gemm2_mfma(pf, ktf[1]); ph_end();
    a_read4(nxt, 8, af);
    ktf_load_h(CHUNKS - 1, 1);
    ph_begin(); gemm1_mfma4(af, 8, s0, s1); ph_end();
    a_read4(nxt, 12, af);
    asm volatile("s_barrier" ::: "memory");
    asm volatile("s_waitcnt lgkmcnt(0)" ::: "memory");
    __builtin_amdgcn_sched_barrier(0);
    __builtin_amdgcn_s_setprio(1);
    gemm1_mfma4(af, 12, s0, s1);
    __builtin_amdgcn_s_setprio(0);
    __builtin_amdgcn_sched_barrier(0);
    exp_pw(nxt, s0, s1);
    asm volatile("s_waitcnt lgkmcnt(0)" ::: "memory");
    asm volatile("s_barrier" ::: "memory");
  }
  // tail B: gemm2(CHUNKS-1) (compiler inserts lgkm/vm waits for pf/ktf use)
  {
    const int cur = (CHUNKS - 1) & 1;
    short8 pf[4];
    pf_read(cur, 0, pf);
    gemm2_mfma(pf, ktf[0]);
    pf_read(cur, 1, pf);
    gemm2_mfma(pf, ktf[1]);
  }

  // ---- epilogue: out += ALPHA * O (out pre-init to Q; atomics L2-coalesce)
  const int colbase = wave * 64 + l15;
#pragma unroll
  for (int tr = 0; tr < 4; ++tr)
#pragma unroll
    for (int td = 0; td < 4; ++td)
#pragma unroll
      for (int r = 0; r < 4; ++r)
        atomicAdd(out + (size_t)(q0 + tr*16 + quad*4 + r) * D + colbase + td*16,
                  ALPHA * oacc[tr][td][r]);
}

extern "C" void kernel_launch(void* const* d_in, const int* in_sizes, int n_in,
                              void* d_out, int out_size, void* d_ws, size_t ws_size,
                              hipStream_t stream) {
  (void)in_sizes; (void)n_in; (void)out_size; (void)ws_size;
  const float* q = (const float*)d_in[0];
  const float* k = (const float*)d_in[1];
  float* out = (float*)d_out;
  unsigned short* Qn  = (unsigned short*)d_ws;          //  4 MB
  unsigned short* Kn  = Qn + (size_t)NB * D;            // 16 MB
  unsigned short* KnT = Kn + (size_t)NK * D;            // 16 MB  (total 36 MB)

  hipLaunchKernelGGL(norm_q_kernel, dim3(NB / 4),  dim3(256),  0, stream, q, out, Qn);
  hipLaunchKernelGGL(norm_k_kernel, dim3(NK / 64), dim3(1024), 0, stream, k, Kn, KnT);
  hipLaunchKernelGGL(fused_kernel, dim3((NB / BQ) * NSPLIT), dim3(512), 0, stream,
                     Qn, Kn, KnT, out);
}

// Round 4
// 318.602 us; speedup vs baseline: 1.4107x; 1.0506x over previous
//
#include <hip/hip_runtime.h>
#include <cstdint>
#include <cstddef>

#define BETA 5.5f
#define ALPHA 0.5f

constexpr int D   = 512;     // feature dim
constexpr int NB  = 4096;    // queries
constexpr int NK  = 16384;   // keys
constexpr int BQ  = 64;      // query tile per block
constexpr int BN  = 64;      // key chunk
constexpr int NSPLIT = 4;
constexpr int NRANGE = NK / NSPLIT;   // 4096
constexpr int CHUNKS = NRANGE / BN;   // 64
constexpr int KROW = D + 8;           // padded LDS row (bf16), 1040 B
constexpr int PROW = BN + 8;          // padded P row: 72

typedef __attribute__((ext_vector_type(8)))  short    short8;
typedef __attribute__((ext_vector_type(4)))  float    floatx4;
typedef __attribute__((ext_vector_type(4)))  uint32_t uint4v;
typedef __attribute__((ext_vector_type(2)))  uint32_t uint2v;

__device__ inline uint32_t f2bf1(float f) {
  union { float f; uint32_t u; } v; v.f = f;
  return (v.u + 0x7FFFu + ((v.u >> 16) & 1u)) >> 16;   // RNE
}
__device__ inline uint32_t pack2(float a, float b) {
  return f2bf1(a) | (f2bf1(b) << 16);
}

__device__ inline void load_lds16(const void* g, void* l) {
  __builtin_amdgcn_global_load_lds(
      (const __attribute__((address_space(1))) uint32_t*)g,
      (__attribute__((address_space(3))) uint32_t*)l, 16, 0, 0);
}

// ---------------- normalize Q -> Qn (bf16), and init out = Q ----------------
__global__ void norm_q_kernel(const float* __restrict__ q,
                              float* __restrict__ out,
                              unsigned short* __restrict__ Qn) {
  const int wave = threadIdx.x >> 6, lane = threadIdx.x & 63;
  const int row = blockIdx.x * 4 + wave;
  const float4* qr = (const float4*)(q + (size_t)row * D);
  float4 a = qr[lane * 2];
  float4 b = qr[lane * 2 + 1];
  float ss = a.x*a.x + a.y*a.y + a.z*a.z + a.w*a.w
           + b.x*b.x + b.y*b.y + b.z*b.z + b.w*b.w;
#pragma unroll
  for (int m = 32; m >= 1; m >>= 1) ss += __shfl_xor(ss, m, 64);
  const float sc = 1.0f / fmaxf(sqrtf(ss), 1e-12f);
  float4* orow = (float4*)(out + (size_t)row * D);
  orow[lane * 2]     = a;
  orow[lane * 2 + 1] = b;
  uint4v w;
  w.x = pack2(a.x*sc, a.y*sc); w.y = pack2(a.z*sc, a.w*sc);
  w.z = pack2(b.x*sc, b.y*sc); w.w = pack2(b.z*sc, b.w*sc);
  *(uint4v*)(Qn + (size_t)row * D + lane * 8) = w;
}

// ------ normalize K -> Kn (bf16 row-major) + KnT (bf16 transposed) ----------
__global__ void norm_k_kernel(const float* __restrict__ k,
                              unsigned short* __restrict__ Kn,
                              unsigned short* __restrict__ KnT) {
  __shared__ unsigned short tile[64 * KROW];
  const int wave = threadIdx.x >> 6, lane = threadIdx.x & 63;
  const int n0 = blockIdx.x * 64;
#pragma unroll
  for (int i = 0; i < 4; ++i) {
    const int rl = wave * 4 + i;
    const int n  = n0 + rl;
    const float4* kr = (const float4*)(k + (size_t)n * D);
    float4 a = kr[lane * 2], b = kr[lane * 2 + 1];
    float ss = a.x*a.x + a.y*a.y + a.z*a.z + a.w*a.w
             + b.x*b.x + b.y*b.y + b.z*b.z + b.w*b.w;
#pragma unroll
    for (int m = 32; m >= 1; m >>= 1) ss += __shfl_xor(ss, m, 64);
    const float sc = 1.0f / fmaxf(sqrtf(ss), 1e-12f);
    uint4v w;
    w.x = pack2(a.x*sc, a.y*sc); w.y = pack2(a.z*sc, a.w*sc);
    w.z = pack2(b.x*sc, b.y*sc); w.w = pack2(b.z*sc, b.w*sc);
    *(uint4v*)(Kn + (size_t)n * D + lane * 8) = w;
    *(uint4v*)&tile[rl * KROW + lane * 8]     = w;
  }
  __syncthreads();
  const int dsub = threadIdx.x >> 3;        // 0..127
  const int nl   = (threadIdx.x & 7) * 8;   // 0..56
#pragma unroll
  for (int iter = 0; iter < 4; ++iter) {
    const int d = iter * 128 + dsub;
    uint4v w;
    w.x = (uint32_t)tile[(nl+0)*KROW + d] | ((uint32_t)tile[(nl+1)*KROW + d] << 16);
    w.y = (uint32_t)tile[(nl+2)*KROW + d] | ((uint32_t)tile[(nl+3)*KROW + d] << 16);
    w.z = (uint32_t)tile[(nl+4)*KROW + d] | ((uint32_t)tile[(nl+5)*KROW + d] << 16);
    w.w = (uint32_t)tile[(nl+6)*KROW + d] | ((uint32_t)tile[(nl+7)*KROW + d] << 16);
    *(uint4v*)(KnT + (size_t)d * NK + n0 + nl) = w;
  }
}

// ---------------- fused: S = Qn Kn^T chunk, P = exp, O += P Kn --------------
// v5 = v4 minus two documented anti-patterns:
//  1. NO sched_barrier(0) anywhere (m141: order-pinning = -42%).
//  2. Single barrier per phase (open only, 7/region vs 13): the mid-region
//     barriers protect nothing (all WAR/RAW hazards already separated by a
//     region-end barrier); closing barriers only added sync skew and forbade
//     early waves from issuing the next load window during their SIMD
//     partner's MFMA cluster.
// Kept: counted vmcnt(8) at region end (stage drained, next-chunk ktf loads
// stay in flight across the barrier), setprio(1) around MFMA clusters,
// R0 data layout / numerics.
__global__ __launch_bounds__(512, 2) void fused_kernel(
    const unsigned short* __restrict__ Qn,
    const unsigned short* __restrict__ Kn,
    const unsigned short* __restrict__ KnT,
    float* __restrict__ out) {
  __shared__ unsigned short K_lds[2][BN * KROW];   // 2 x 66.5 KB
  __shared__ unsigned short P_lds[2][BQ * PROW];   // 2 x 9.2 KB  (151.5 KB)

  const int tid  = threadIdx.x;
  const int wave = tid >> 6, lane = tid & 63;
  const int l15  = lane & 15, quad = lane >> 4;
  const int nsplit = blockIdx.x & (NSPLIT - 1);
  const int qtile  = blockIdx.x >> 2;           // 0..63
  const int q0     = qtile * BQ;
  const int nbase  = nsplit * NRANGE;
  const int tb = wave & 3, nh = wave >> 2;

  // Q B-fragments in registers: wave's 16-col b-tile, all 512 d (64 VGPR)
  short8 qf[16];
  {
    const unsigned short* qrow = Qn + (size_t)(q0 + tb * 16 + l15) * D + quad * 8;
#pragma unroll
    for (int kb = 0; kb < 16; ++kb) qf[kb] = *(const short8*)(qrow + kb * 32);
  }

  floatx4 oacc[4][4] = {};   // wave's 64x64 O slice (AGPR)
  short8 ktf[2][4];          // KnT B-frags (32 VGPR)

  const unsigned short* ktrow = KnT + (size_t)(wave*64 + l15) * NK + nbase + quad*8;

  // ---- helpers ---------------------------------------------------------
  auto stage = [&](int ch, int buf) {
#pragma unroll
    for (int i = 0; i < 8; ++i) {
      const int row = wave * 8 + i;
      load_lds16(Kn + (size_t)(nbase + ch*BN + row) * D + lane * 8,
                 &K_lds[buf][row * KROW]);
    }
  };
  auto ktf_load_h = [&](int ch, int kb2) {
#pragma unroll
    for (int td = 0; td < 4; ++td)
      ktf[kb2][td] = *(const short8*)(ktrow + (size_t)td*16*NK + ch*BN + kb2*32);
  };
  auto pf_read = [&](int pbuf, int kb2, short8* pf) {
#pragma unroll
    for (int tr = 0; tr < 4; ++tr)
      pf[tr] = *(const short8*)&P_lds[pbuf][(tr*16 + l15) * PROW + kb2*32 + quad*8];
  };
  auto gemm2_mfma = [&](const short8* pf, const short8* kt) {
#pragma unroll
    for (int td = 0; td < 4; ++td)
#pragma unroll
      for (int tr = 0; tr < 4; ++tr)
        oacc[tr][td] = __builtin_amdgcn_mfma_f32_16x16x32_bf16(
            pf[tr], kt[td], oacc[tr][td], 0, 0, 0);
  };
  auto a_read4 = [&](int buf, int kb0, short8* af) {
#pragma unroll
    for (int i = 0; i < 4; ++i) {
      af[2*i]   = *(const short8*)&K_lds[buf][(nh*32 +      l15) * KROW + (kb0+i)*32 + quad*8];
      af[2*i+1] = *(const short8*)&K_lds[buf][(nh*32 + 16 + l15) * KROW + (kb0+i)*32 + quad*8];
    }
  };
  auto gemm1_mfma4 = [&](const short8* af, int kb0, floatx4& s0, floatx4& s1) {
#pragma unroll
    for (int i = 0; i < 4; ++i) {
      s0 = __builtin_amdgcn_mfma_f32_16x16x32_bf16(af[2*i],   qf[kb0+i], s0, 0, 0, 0);
      s1 = __builtin_amdgcn_mfma_f32_16x16x32_bf16(af[2*i+1], qf[kb0+i], s1, 0, 0, 0);
    }
  };
  auto exp_pw = [&](int buf, const floatx4& s0, const floatx4& s1) {
    const int prow = (tb * 16 + l15) * PROW;
    uint2v w0, w1;
    w0.x = pack2(__expf(BETA * (s0[0] - 1.f)), __expf(BETA * (s0[1] - 1.f)));
    w0.y = pack2(__expf(BETA * (s0[2] - 1.f)), __expf(BETA * (s0[3] - 1.f)));
    w1.x = pack2(__expf(BETA * (s1[0] - 1.f)), __expf(BETA * (s1[1] - 1.f)));
    w1.y = pack2(__expf(BETA * (s1[2] - 1.f)), __expf(BETA * (s1[3] - 1.f)));
    *(uint2v*)&P_lds[buf][prow + (nh*2 + 0) * 16 + quad * 4] = w0;
    *(uint2v*)&P_lds[buf][prow + (nh*2 + 1) * 16 + quad * 4] = w1;
  };
  // phase open: barrier (phase-lock the 8 waves), drain own ds ops, boost
  auto ph = [&]() {
    asm volatile("s_barrier" ::: "memory");
    asm volatile("s_waitcnt lgkmcnt(0)" ::: "memory");
    __builtin_amdgcn_s_setprio(1);
  };
  auto ph_done = [&]() { __builtin_amdgcn_s_setprio(0); };
  // ----------------------------------------------------------------------

  // prologue: stage(0)+ktf(0); wait stage(0); {stage(1); GEMM1(0); P(0)}
  stage(0, 0);
  ktf_load_h(0, 0); ktf_load_h(0, 1);
  asm volatile("s_waitcnt vmcnt(8)" ::: "memory");   // stage(0) done, ktf in flight
  asm volatile("s_barrier" ::: "memory");
  {
    stage(1, 1);
    floatx4 s0 = {0.f,0.f,0.f,0.f}, s1 = {0.f,0.f,0.f,0.f};
    short8 af[8];
#pragma unroll
    for (int g = 0; g < 4; ++g) {
      a_read4(0, g*4, af);
      gemm1_mfma4(af, g*4, s0, s1);
    }
    exp_pw(0, s0, s1);
  }
  asm volatile("s_waitcnt vmcnt(0) lgkmcnt(0)" ::: "memory");  // stage(1)+P(0) done
  asm volatile("s_barrier" ::: "memory");

  // steady state: region c = 6 phases, single barrier each. gemm2 consumes
  // chunk c (P_lds[cur], ktf), gemm1 computes chunk c+1 -> P_lds[nxt].
#pragma unroll 1
  for (int c = 0; c + 2 < CHUNKS; ++c) {
    const int cur = c & 1, nxt = cur ^ 1;
    floatx4 s0 = {0.f,0.f,0.f,0.f}, s1 = {0.f,0.f,0.f,0.f};
    short8 pf[4], af[8];
    // A: stage(c+2) + P reads kb2=0 -> gemm2 half0 (ktf[0] = chunk c)
    stage(c + 2, cur);
    pf_read(cur, 0, pf);
    ph(); gemm2_mfma(pf, ktf[0]); ph_done();
    // B1: gemm1 kb0-3
    a_read4(nxt, 0, af);
    ph(); gemm1_mfma4(af, 0, s0, s1); ph_done();
    // B2: gemm1 kb4-7
    a_read4(nxt, 4, af);
    ph(); gemm1_mfma4(af, 4, s0, s1); ph_done();
    // C: P reads kb2=1 + ktf(c+1) half0 -> gemm2 half1 (ktf[1] = chunk c)
    pf_read(cur, 1, pf);
    ktf_load_h(c + 1, 0);
    ph(); gemm2_mfma(pf, ktf[1]); ph_done();
    // D1: gemm1 kb8-11 + ktf(c+1) half1
    a_read4(nxt, 8, af);
    ktf_load_h(c + 1, 1);
    ph(); gemm1_mfma4(af, 8, s0, s1); ph_done();
    // D2: gemm1 kb12-15 -> exp -> P(c+1); region-end counted barrier
    a_read4(nxt, 12, af);
    ph(); gemm1_mfma4(af, 12, s0, s1); ph_done();
    exp_pw(nxt, s0, s1);
    // P writes drained; stage(c+2) drained; ktf(c+1) [8] stay in flight
    asm volatile("s_waitcnt vmcnt(8) lgkmcnt(0)" ::: "memory");
    asm volatile("s_barrier" ::: "memory");
  }
  // tail A: region CHUNKS-2 (no staging): gemm2(CHUNKS-2) + gemm1(CHUNKS-1)
  {
    const int c = CHUNKS - 2, cur = c & 1, nxt = cur ^ 1;
    floatx4 s0 = {0.f,0.f,0.f,0.f}, s1 = {0.f,0.f,0.f,0.f};
    short8 pf[4], af[8];
    pf_read(cur, 0, pf);
    ph(); gemm2_mfma(pf, ktf[0]); ph_done();
    a_read4(nxt, 0, af);
    ph(); gemm1_mfma4(af, 0, s0, s1); ph_done();
    a_read4(nxt, 4, af);
    ph(); gemm1_mfma4(af, 4, s0, s1); ph_done();
    pf_read(cur, 1, pf);
    ktf_load_h(CHUNKS - 1, 0);
    ph(); gemm2_mfma(pf, ktf[1]); ph_done();
    a_read4(nxt, 8, af);
    ktf_load_h(CHUNKS - 1, 1);
    ph(); gemm1_mfma4(af, 8, s0, s1); ph_done();
    a_read4(nxt, 12, af);
    ph(); gemm1_mfma4(af, 12, s0, s1); ph_done();
    exp_pw(nxt, s0, s1);
    asm volatile("s_waitcnt lgkmcnt(0)" ::: "memory");
    asm volatile("s_barrier" ::: "memory");
  }
  // tail B: gemm2(CHUNKS-1) (compiler inserts lgkm/vm waits for pf/ktf use)
  {
    const int cur = (CHUNKS - 1) & 1;
    short8 pf[4];
    pf_read(cur, 0, pf);
    gemm2_mfma(pf, ktf[0]);
    pf_read(cur, 1, pf);
    gemm2_mfma(pf, ktf[1]);
  }

  // ---- epilogue: out += ALPHA * O (out pre-init to Q; atomics L2-coalesce)
  const int colbase = wave * 64 + l15;
#pragma unroll
  for (int tr = 0; tr < 4; ++tr)
#pragma unroll
    for (int td = 0; td < 4; ++td)
#pragma unroll
      for (int r = 0; r < 4; ++r)
        atomicAdd(out + (size_t)(q0 + tr*16 + quad*4 + r) * D + colbase + td*16,
                  ALPHA * oacc[tr][td][r]);
}

extern "C" void kernel_launch(void* const* d_in, const int* in_sizes, int n_in,
                              void* d_out, int out_size, void* d_ws, size_t ws_size,
                              hipStream_t stream) {
  (void)in_sizes; (void)n_in; (void)out_size; (void)ws_size;
  const float* q = (const float*)d_in[0];
  const float* k = (const float*)d_in[1];
  float* out = (float*)d_out;
  unsigned short* Qn  = (unsigned short*)d_ws;          //  4 MB
  unsigned short* Kn  = Qn + (size_t)NB * D;            // 16 MB
  unsigned short* KnT = Kn + (size_t)NK * D;            // 16 MB  (total 36 MB)

  hipLaunchKernelGGL(norm_q_kernel, dim3(NB / 4),  dim3(256),  0, stream, q, out, Qn);
  hipLaunchKernelGGL(norm_k_kernel, dim3(NK / 64), dim3(1024), 0, stream, k, Kn, KnT);
  hipLaunchKernelGGL(fused_kernel, dim3((NB / BQ) * NSPLIT), dim3(512), 0, stream,
                     Qn, Kn, KnT, out);
}

// Round 5
// 280.119 us; speedup vs baseline: 1.6045x; 1.1374x over previous
//
#include <hip/hip_runtime.h>
#include <cstdint>
#include <cstddef>

#define BETA 5.5f
#define ALPHA 0.5f

constexpr int D   = 512;     // feature dim
constexpr int NB  = 4096;    // queries
constexpr int NK  = 16384;   // keys
constexpr int BQ  = 64;      // query tile per block
constexpr int BN  = 64;      // key chunk
constexpr int NSPLIT = 4;
constexpr int NRANGE = NK / NSPLIT;   // 4096
constexpr int CHUNKS = NRANGE / BN;   // 64
constexpr int KROW = D + 8;           // padded LDS row (bf16), 1040 B
constexpr int PROW = BN + 8;          // padded P row: 72

typedef __attribute__((ext_vector_type(8)))  short    short8;
typedef __attribute__((ext_vector_type(4)))  float    floatx4;
typedef __attribute__((ext_vector_type(4)))  uint32_t uint4v;
typedef __attribute__((ext_vector_type(2)))  uint32_t uint2v;

__device__ inline uint32_t f2bf1(float f) {
  union { float f; uint32_t u; } v; v.f = f;
  return (v.u + 0x7FFFu + ((v.u >> 16) & 1u)) >> 16;   // RNE
}
__device__ inline uint32_t pack2(float a, float b) {
  return f2bf1(a) | (f2bf1(b) << 16);
}

__device__ inline void load_lds16(const void* g, void* l) {
  __builtin_amdgcn_global_load_lds(
      (const __attribute__((address_space(1))) uint32_t*)g,
      (__attribute__((address_space(3))) uint32_t*)l, 16, 0, 0);
}

// ---------------- normalize Q -> Qn (bf16), and init out = Q ----------------
__global__ void norm_q_kernel(const float* __restrict__ q,
                              float* __restrict__ out,
                              unsigned short* __restrict__ Qn) {
  const int wave = threadIdx.x >> 6, lane = threadIdx.x & 63;
  const int row = blockIdx.x * 4 + wave;
  const float4* qr = (const float4*)(q + (size_t)row * D);
  float4 a = qr[lane * 2];
  float4 b = qr[lane * 2 + 1];
  float ss = a.x*a.x + a.y*a.y + a.z*a.z + a.w*a.w
           + b.x*b.x + b.y*b.y + b.z*b.z + b.w*b.w;
#pragma unroll
  for (int m = 32; m >= 1; m >>= 1) ss += __shfl_xor(ss, m, 64);
  const float sc = 1.0f / fmaxf(sqrtf(ss), 1e-12f);
  float4* orow = (float4*)(out + (size_t)row * D);
  orow[lane * 2]     = a;
  orow[lane * 2 + 1] = b;
  uint4v w;
  w.x = pack2(a.x*sc, a.y*sc); w.y = pack2(a.z*sc, a.w*sc);
  w.z = pack2(b.x*sc, b.y*sc); w.w = pack2(b.z*sc, b.w*sc);
  *(uint4v*)(Qn + (size_t)row * D + lane * 8) = w;
}

// ------ normalize K -> Kn (bf16 row-major) + KnT (bf16 transposed) ----------
__global__ void norm_k_kernel(const float* __restrict__ k,
                              unsigned short* __restrict__ Kn,
                              unsigned short* __restrict__ KnT) {
  __shared__ unsigned short tile[64 * KROW];
  const int wave = threadIdx.x >> 6, lane = threadIdx.x & 63;
  const int n0 = blockIdx.x * 64;
#pragma unroll
  for (int i = 0; i < 4; ++i) {
    const int rl = wave * 4 + i;
    const int n  = n0 + rl;
    const float4* kr = (const float4*)(k + (size_t)n * D);
    float4 a = kr[lane * 2], b = kr[lane * 2 + 1];
    float ss = a.x*a.x + a.y*a.y + a.z*a.z + a.w*a.w
             + b.x*b.x + b.y*b.y + b.z*b.z + b.w*b.w;
#pragma unroll
    for (int m = 32; m >= 1; m >>= 1) ss += __shfl_xor(ss, m, 64);
    const float sc = 1.0f / fmaxf(sqrtf(ss), 1e-12f);
    uint4v w;
    w.x = pack2(a.x*sc, a.y*sc); w.y = pack2(a.z*sc, a.w*sc);
    w.z = pack2(b.x*sc, b.y*sc); w.w = pack2(b.z*sc, b.w*sc);
    *(uint4v*)(Kn + (size_t)n * D + lane * 8) = w;
    *(uint4v*)&tile[rl * KROW + lane * 8]     = w;
  }
  __syncthreads();
  const int dsub = threadIdx.x >> 3;        // 0..127
  const int nl   = (threadIdx.x & 7) * 8;   // 0..56
#pragma unroll
  for (int iter = 0; iter < 4; ++iter) {
    const int d = iter * 128 + dsub;
    uint4v w;
    w.x = (uint32_t)tile[(nl+0)*KROW + d] | ((uint32_t)tile[(nl+1)*KROW + d] << 16);
    w.y = (uint32_t)tile[(nl+2)*KROW + d] | ((uint32_t)tile[(nl+3)*KROW + d] << 16);
    w.z = (uint32_t)tile[(nl+4)*KROW + d] | ((uint32_t)tile[(nl+5)*KROW + d] << 16);
    w.w = (uint32_t)tile[(nl+6)*KROW + d] | ((uint32_t)tile[(nl+7)*KROW + d] << 16);
    *(uint4v*)(KnT + (size_t)d * NK + n0 + nl) = w;
  }
}

// ---------------- fused: S = Qn Kn^T chunk, P = exp, O += P Kn --------------
// v6: intra-region SOFTWARE PIPELINE, zero intra-region barriers.
// All cross-wave data (P, staged K) is consumed strictly after the region
// boundary, so the mid-region barriers of R0-R4 protected nothing; they only
// phase-locked the 2 waves/SIMD and exposed raw LDS latency (each MFMA
// cluster's ds_reads were issued ~0 cycles before the wait consuming them —
// the invariant across all four 240us-plateau schedules). Here each
// cluster's operand reads are issued BEFORE the previous cluster's MFMAs
// (double-buffered af/pf register sets); the compiler emits its own counted
// lgkmcnt per use (m97: near-optimal; manual asm waits risk rule-#18
// hoisting). Region boundary keeps: vmcnt(8) (stage drained, next-chunk ktf
// in flight) + lgkmcnt(0) (P writes visible) + one s_barrier.
__global__ __launch_bounds__(512, 2) void fused_kernel(
    const unsigned short* __restrict__ Qn,
    const unsigned short* __restrict__ Kn,
    const unsigned short* __restrict__ KnT,
    float* __restrict__ out) {
  __shared__ unsigned short K_lds[2][BN * KROW];   // 2 x 66.5 KB
  __shared__ unsigned short P_lds[2][BQ * PROW];   // 2 x 9.2 KB  (151.5 KB)

  const int tid  = threadIdx.x;
  const int wave = tid >> 6, lane = tid & 63;
  const int l15  = lane & 15, quad = lane >> 4;
  const int nsplit = blockIdx.x & (NSPLIT - 1);
  const int qtile  = blockIdx.x >> 2;           // 0..63
  const int q0     = qtile * BQ;
  const int nbase  = nsplit * NRANGE;
  const int tb = wave & 3, nh = wave >> 2;

  // Q B-fragments in registers: wave's 16-col b-tile, all 512 d (64 VGPR)
  short8 qf[16];
  {
    const unsigned short* qrow = Qn + (size_t)(q0 + tb * 16 + l15) * D + quad * 8;
#pragma unroll
    for (int kb = 0; kb < 16; ++kb) qf[kb] = *(const short8*)(qrow + kb * 32);
  }

  floatx4 oacc[4][4] = {};   // wave's 64x64 O slice
  short8 ktf[2][4];          // KnT B-frags (32 VGPR)

  const unsigned short* ktrow = KnT + (size_t)(wave*64 + l15) * NK + nbase + quad*8;

  // ---- helpers ---------------------------------------------------------
  auto stage = [&](int ch, int buf) {
#pragma unroll
    for (int i = 0; i < 8; ++i) {
      const int row = wave * 8 + i;
      load_lds16(Kn + (size_t)(nbase + ch*BN + row) * D + lane * 8,
                 &K_lds[buf][row * KROW]);
    }
  };
  auto ktf_load_h = [&](int ch, int kb2) {
#pragma unroll
    for (int td = 0; td < 4; ++td)
      ktf[kb2][td] = *(const short8*)(ktrow + (size_t)td*16*NK + ch*BN + kb2*32);
  };
  auto pf_read = [&](int pbuf, int kb2, short8* pf) {
#pragma unroll
    for (int tr = 0; tr < 4; ++tr)
      pf[tr] = *(const short8*)&P_lds[pbuf][(tr*16 + l15) * PROW + kb2*32 + quad*8];
  };
  auto gemm2_mfma = [&](const short8* pf, const short8* kt) {
    __builtin_amdgcn_s_setprio(1);
#pragma unroll
    for (int td = 0; td < 4; ++td)
#pragma unroll
      for (int tr = 0; tr < 4; ++tr)
        oacc[tr][td] = __builtin_amdgcn_mfma_f32_16x16x32_bf16(
            pf[tr], kt[td], oacc[tr][td], 0, 0, 0);
    __builtin_amdgcn_s_setprio(0);
  };
  auto a_read4 = [&](int buf, int kb0, short8* af) {
#pragma unroll
    for (int i = 0; i < 4; ++i) {
      af[2*i]   = *(const short8*)&K_lds[buf][(nh*32 +      l15) * KROW + (kb0+i)*32 + quad*8];
      af[2*i+1] = *(const short8*)&K_lds[buf][(nh*32 + 16 + l15) * KROW + (kb0+i)*32 + quad*8];
    }
  };
  auto gemm1_mfma4 = [&](const short8* af, int kb0, floatx4& s0, floatx4& s1) {
    __builtin_amdgcn_s_setprio(1);
#pragma unroll
    for (int i = 0; i < 4; ++i) {
      s0 = __builtin_amdgcn_mfma_f32_16x16x32_bf16(af[2*i],   qf[kb0+i], s0, 0, 0, 0);
      s1 = __builtin_amdgcn_mfma_f32_16x16x32_bf16(af[2*i+1], qf[kb0+i], s1, 0, 0, 0);
    }
    __builtin_amdgcn_s_setprio(0);
  };
  auto exp_pw = [&](int buf, const floatx4& s0, const floatx4& s1) {
    const int prow = (tb * 16 + l15) * PROW;
    uint2v w0, w1;
    w0.x = pack2(__expf(BETA * (s0[0] - 1.f)), __expf(BETA * (s0[1] - 1.f)));
    w0.y = pack2(__expf(BETA * (s0[2] - 1.f)), __expf(BETA * (s0[3] - 1.f)));
    w1.x = pack2(__expf(BETA * (s1[0] - 1.f)), __expf(BETA * (s1[1] - 1.f)));
    w1.y = pack2(__expf(BETA * (s1[2] - 1.f)), __expf(BETA * (s1[3] - 1.f)));
    *(uint2v*)&P_lds[buf][prow + (nh*2 + 0) * 16 + quad * 4] = w0;
    *(uint2v*)&P_lds[buf][prow + (nh*2 + 1) * 16 + quad * 4] = w1;
  };
  // ----------------------------------------------------------------------

  // prologue: stage(0)+ktf(0); stage(0) visible; {stage(1); GEMM1(0); P(0)}
  stage(0, 0);
  ktf_load_h(0, 0); ktf_load_h(0, 1);
  asm volatile("s_waitcnt vmcnt(8)" ::: "memory");   // stage(0) done, ktf in flight
  asm volatile("s_barrier" ::: "memory");
  {
    stage(1, 1);
    floatx4 s0 = {0.f,0.f,0.f,0.f}, s1 = {0.f,0.f,0.f,0.f};
    short8 afA[8], afB[8];
    a_read4(0, 0, afA);                        // pipelined prologue gemm1
    a_read4(0, 4, afB);
    gemm1_mfma4(afA, 0, s0, s1);
    a_read4(0, 8, afA);
    gemm1_mfma4(afB, 4, s0, s1);
    a_read4(0, 12, afB);
    gemm1_mfma4(afA, 8, s0, s1);
    gemm1_mfma4(afB, 12, s0, s1);
    exp_pw(0, s0, s1);
  }
  // one-time full drain: stage(1) visible + P(0) visible
  asm volatile("s_waitcnt vmcnt(0) lgkmcnt(0)" ::: "memory");
  asm volatile("s_barrier" ::: "memory");

  // steady state: region c, NO intra-region barriers. Entry invariant:
  // K_lds[nxt]=chunk c+1 ready, P_lds[cur]=P(c) ready, ktf=chunk c,
  // 8 ktf(c) loads... (drained by compiler waits on first ktf use).
#pragma unroll 1
  for (int c = 0; c + 2 < CHUNKS; ++c) {
    const int cur = c & 1, nxt = cur ^ 1;
    floatx4 s0 = {0.f,0.f,0.f,0.f}, s1 = {0.f,0.f,0.f,0.f};
    short8 pf0[4], pf1[4], afA[8], afB[8];
    stage(c + 2, cur);                 // K_lds[cur] free since region c-1
    pf_read(cur, 0, pf0);              // operands for cluster 1
    a_read4(nxt, 0, afA);              // operands for cluster 2
    gemm2_mfma(pf0, ktf[0]);           // cluster 1 (P(c) x chunk-c cols)
    a_read4(nxt, 4, afB);              // operands for cluster 3
    gemm1_mfma4(afA, 0, s0, s1);       // cluster 2 (S(c+1) kb0-3)
    pf_read(cur, 1, pf1);              // operands for cluster 4
    gemm1_mfma4(afB, 4, s0, s1);       // cluster 3 (kb4-7)
    a_read4(nxt, 8, afA);              // operands for cluster 5
    ktf_load_h(c + 1, 0);              // WAR on ktf[0] (consumed by cluster 1)
    gemm2_mfma(pf1, ktf[1]);           // cluster 4
    a_read4(nxt, 12, afB);             // operands for cluster 6
    ktf_load_h(c + 1, 1);
    gemm1_mfma4(afA, 8, s0, s1);       // cluster 5 (kb8-11)
    gemm1_mfma4(afB, 12, s0, s1);      // cluster 6 (kb12-15)
    exp_pw(nxt, s0, s1);               // P(c+1) -> P_lds[nxt]
    // stage(c+2) drained (8 oldest); ktf(c+1) 8 stay in flight; P visible
    asm volatile("s_waitcnt vmcnt(8) lgkmcnt(0)" ::: "memory");
    asm volatile("s_barrier" ::: "memory");
  }
  // tail A: region CHUNKS-2 (no staging): gemm2(CHUNKS-2) + gemm1(CHUNKS-1)
  {
    const int cur = (CHUNKS - 2) & 1, nxt = cur ^ 1;
    floatx4 s0 = {0.f,0.f,0.f,0.f}, s1 = {0.f,0.f,0.f,0.f};
    short8 pf0[4], pf1[4], afA[8], afB[8];
    pf_read(cur, 0, pf0);
    a_read4(nxt, 0, afA);
    gemm2_mfma(pf0, ktf[0]);
    a_read4(nxt, 4, afB);
    gemm1_mfma4(afA, 0, s0, s1);
    pf_read(cur, 1, pf1);
    gemm1_mfma4(afB, 4, s0, s1);
    a_read4(nxt, 8, afA);
    ktf_load_h(CHUNKS - 1, 0);
    gemm2_mfma(pf1, ktf[1]);
    a_read4(nxt, 12, afB);
    ktf_load_h(CHUNKS - 1, 1);
    gemm1_mfma4(afA, 8, s0, s1);
    gemm1_mfma4(afB, 12, s0, s1);
    exp_pw(nxt, s0, s1);
    asm volatile("s_waitcnt lgkmcnt(0)" ::: "memory");
    asm volatile("s_barrier" ::: "memory");
  }
  // tail B: gemm2(CHUNKS-1) (compiler inserts lgkm/vm waits for pf/ktf use)
  {
    const int cur = (CHUNKS - 1) & 1;
    short8 pf0[4], pf1[4];
    pf_read(cur, 0, pf0);
    pf_read(cur, 1, pf1);
    gemm2_mfma(pf0, ktf[0]);
    gemm2_mfma(pf1, ktf[1]);
  }

  // ---- epilogue: out += ALPHA * O (out pre-init to Q; atomics L2-coalesce)
  const int colbase = wave * 64 + l15;
#pragma unroll
  for (int tr = 0; tr < 4; ++tr)
#pragma unroll
    for (int td = 0; td < 4; ++td)
#pragma unroll
      for (int r = 0; r < 4; ++r)
        atomicAdd(out + (size_t)(q0 + tr*16 + quad*4 + r) * D + colbase + td*16,
                  ALPHA * oacc[tr][td][r]);
}

extern "C" void kernel_launch(void* const* d_in, const int* in_sizes, int n_in,
                              void* d_out, int out_size, void* d_ws, size_t ws_size,
                              hipStream_t stream) {
  (void)in_sizes; (void)n_in; (void)out_size; (void)ws_size;
  const float* q = (const float*)d_in[0];
  const float* k = (const float*)d_in[1];
  float* out = (float*)d_out;
  unsigned short* Qn  = (unsigned short*)d_ws;          //  4 MB
  unsigned short* Kn  = Qn + (size_t)NB * D;            // 16 MB
  unsigned short* KnT = Kn + (size_t)NK * D;            // 16 MB  (total 36 MB)

  hipLaunchKernelGGL(norm_q_kernel, dim3(NB / 4),  dim3(256),  0, stream, q, out, Qn);
  hipLaunchKernelGGL(norm_k_kernel, dim3(NK / 64), dim3(1024), 0, stream, k, Kn, KnT);
  hipLaunchKernelGGL(fused_kernel, dim3((NB / BQ) * NSPLIT), dim3(512), 0, stream,
                     Qn, Kn, KnT, out);
}

// Round 6
// 266.477 us; speedup vs baseline: 1.6866x; 1.0512x over previous
//
#include <hip/hip_runtime.h>
#include <cstdint>
#include <cstddef>

#define BETA 5.5f
#define ALPHA 0.5f

constexpr int D   = 512;     // feature dim
constexpr int NB  = 4096;    // queries
constexpr int NK  = 16384;   // keys
constexpr int BQ  = 64;      // query tile per block
constexpr int BN  = 64;      // key chunk
constexpr int NSPLIT = 4;
constexpr int NRANGE = NK / NSPLIT;   // 4096
constexpr int CHUNKS = NRANGE / BN;   // 64
constexpr int KROW = D + 8;           // padded LDS row (bf16), 1040 B
constexpr int PROW = BN + 8;          // padded P row: 72

typedef __attribute__((ext_vector_type(8)))  short    short8;
typedef __attribute__((ext_vector_type(4)))  float    floatx4;
typedef __attribute__((ext_vector_type(4)))  uint32_t uint4v;
typedef __attribute__((ext_vector_type(2)))  uint32_t uint2v;

__device__ inline uint32_t f2bf1(float f) {
  union { float f; uint32_t u; } v; v.f = f;
  return (v.u + 0x7FFFu + ((v.u >> 16) & 1u)) >> 16;   // RNE
}
__device__ inline uint32_t pack2(float a, float b) {
  return f2bf1(a) | (f2bf1(b) << 16);
}

__device__ inline void load_lds16(const void* g, void* l) {
  __builtin_amdgcn_global_load_lds(
      (const __attribute__((address_space(1))) uint32_t*)g,
      (__attribute__((address_space(3))) uint32_t*)l, 16, 0, 0);
}

// ---------------- normalize Q -> Qn (bf16), and init out = Q ----------------
__global__ void norm_q_kernel(const float* __restrict__ q,
                              float* __restrict__ out,
                              unsigned short* __restrict__ Qn) {
  const int wave = threadIdx.x >> 6, lane = threadIdx.x & 63;
  const int row = blockIdx.x * 4 + wave;
  const float4* qr = (const float4*)(q + (size_t)row * D);
  float4 a = qr[lane * 2];
  float4 b = qr[lane * 2 + 1];
  float ss = a.x*a.x + a.y*a.y + a.z*a.z + a.w*a.w
           + b.x*b.x + b.y*b.y + b.z*b.z + b.w*b.w;
#pragma unroll
  for (int m = 32; m >= 1; m >>= 1) ss += __shfl_xor(ss, m, 64);
  const float sc = 1.0f / fmaxf(sqrtf(ss), 1e-12f);
  float4* orow = (float4*)(out + (size_t)row * D);
  orow[lane * 2]     = a;
  orow[lane * 2 + 1] = b;
  uint4v w;
  w.x = pack2(a.x*sc, a.y*sc); w.y = pack2(a.z*sc, a.w*sc);
  w.z = pack2(b.x*sc, b.y*sc); w.w = pack2(b.z*sc, b.w*sc);
  *(uint4v*)(Qn + (size_t)row * D + lane * 8) = w;
}

// ------ normalize K -> Kn (bf16 row-major) + KnT (bf16 transposed) ----------
__global__ void norm_k_kernel(const float* __restrict__ k,
                              unsigned short* __restrict__ Kn,
                              unsigned short* __restrict__ KnT) {
  __shared__ unsigned short tile[64 * KROW];
  const int wave = threadIdx.x >> 6, lane = threadIdx.x & 63;
  const int n0 = blockIdx.x * 64;
#pragma unroll
  for (int i = 0; i < 4; ++i) {
    const int rl = wave * 4 + i;
    const int n  = n0 + rl;
    const float4* kr = (const float4*)(k + (size_t)n * D);
    float4 a = kr[lane * 2], b = kr[lane * 2 + 1];
    float ss = a.x*a.x + a.y*a.y + a.z*a.z + a.w*a.w
             + b.x*b.x + b.y*b.y + b.z*b.z + b.w*b.w;
#pragma unroll
    for (int m = 32; m >= 1; m >>= 1) ss += __shfl_xor(ss, m, 64);
    const float sc = 1.0f / fmaxf(sqrtf(ss), 1e-12f);
    uint4v w;
    w.x = pack2(a.x*sc, a.y*sc); w.y = pack2(a.z*sc, a.w*sc);
    w.z = pack2(b.x*sc, b.y*sc); w.w = pack2(b.z*sc, b.w*sc);
    *(uint4v*)(Kn + (size_t)n * D + lane * 8) = w;
    *(uint4v*)&tile[rl * KROW + lane * 8]     = w;
  }
  __syncthreads();
  const int dsub = threadIdx.x >> 3;        // 0..127
  const int nl   = (threadIdx.x & 7) * 8;   // 0..56
#pragma unroll
  for (int iter = 0; iter < 4; ++iter) {
    const int d = iter * 128 + dsub;
    uint4v w;
    w.x = (uint32_t)tile[(nl+0)*KROW + d] | ((uint32_t)tile[(nl+1)*KROW + d] << 16);
    w.y = (uint32_t)tile[(nl+2)*KROW + d] | ((uint32_t)tile[(nl+3)*KROW + d] << 16);
    w.z = (uint32_t)tile[(nl+4)*KROW + d] | ((uint32_t)tile[(nl+5)*KROW + d] << 16);
    w.w = (uint32_t)tile[(nl+6)*KROW + d] | ((uint32_t)tile[(nl+7)*KROW + d] << 16);
    *(uint4v*)(KnT + (size_t)d * NK + n0 + nl) = w;
  }
}

// ---------------- fused: S = Qn Kn^T chunk, P = exp, O += P Kn --------------
// v7: R1's wave-specialized tiling (verified numerics) x R5's pipelined
// single-barrier schedule (verified +15%).
//   S-waves 0-3: 32q x 32n S-tiles, qf[2][16] (128 reg), 32 A-reads/region
//     -> block A-reads 128/region (was 256: the 4x tb-duplication halved).
//   O-waves 4-7: 64q x 128d O-slices, oacc[4][8]+ktf[2][8], 8 P-reads/region
//     -> block P-reads 32 (was 64); O's MFMAs never touch the hot K_lds.
// LDS b128 reads/region: 320 -> 160 (conflicts scale with read count: R1
// measured 1.15e7 vs 2.2e7 at identical tiling). One barrier per region;
// S-branch drains vmcnt(0) (its staging) + lgkmcnt(0) (P visibility);
// O-branch barriers carry NO waits (compiler inserts counted vmcnt at ktf
// use, so next-chunk ktf loads stay in flight across the barrier).
// Barrier counts: S = 2 + 62 + 1 = 65, O = 2 + 62 + 1 = 65. Matched.
__global__ __launch_bounds__(512, 2) void fused_kernel(
    const unsigned short* __restrict__ Qn,
    const unsigned short* __restrict__ Kn,
    const unsigned short* __restrict__ KnT,
    float* __restrict__ out) {
  __shared__ unsigned short K_lds[2][BN * KROW];   // 2 x 66.5 KB
  __shared__ unsigned short P_lds[2][BQ * PROW];   // 2 x 9.2 KB  (151.5 KB)

  const int tid  = threadIdx.x;
  const int wave = tid >> 6, lane = tid & 63;
  const int l15  = lane & 15, quad = lane >> 4;
  const int nsplit = blockIdx.x & (NSPLIT - 1);
  const int qtile  = blockIdx.x >> 2;           // 0..63
  const int q0     = qtile * BQ;
  const int nbase  = nsplit * NRANGE;

  if (wave < 4) {
    // ================= S-producer: GEMM1 + exp -> P_lds ===================
    const int sw = wave;
    const int qh = wave & 1, nh = wave >> 1;
    // Q B-fragments: 32 q-cols x all 512 k -> 128 VGPR (persistent)
    short8 qf[2][16];
    {
      const unsigned short* qrow0 = Qn + (size_t)(q0 + qh * 32 + l15) * D + quad * 8;
#pragma unroll
      for (int qt = 0; qt < 2; ++qt)
#pragma unroll
        for (int kb = 0; kb < 16; ++kb)
          qf[qt][kb] = *(const short8*)(qrow0 + (size_t)qt * 16 * D + kb * 32);
    }

    floatx4 sacc[2][2];

    auto stage = [&](int ch, int buf) {
#pragma unroll
      for (int i = 0; i < 16; ++i) {
        const int row = sw * 16 + i;
        load_lds16(Kn + (size_t)(nbase + ch * BN + row) * D + lane * 8,
                   &K_lds[buf][row * KROW]);
      }
    };
    auto a_read8 = [&](int buf, int kb0, short8* af) {
#pragma unroll
      for (int i = 0; i < 4; ++i) {
        af[2*i]   = *(const short8*)&K_lds[buf][(nh*32 +      l15) * KROW + (kb0+i)*32 + quad*8];
        af[2*i+1] = *(const short8*)&K_lds[buf][(nh*32 + 16 + l15) * KROW + (kb0+i)*32 + quad*8];
      }
    };
    auto g1c = [&](const short8* af, int kb0) {
      __builtin_amdgcn_s_setprio(1);
#pragma unroll
      for (int i = 0; i < 4; ++i) {
        sacc[0][0] = __builtin_amdgcn_mfma_f32_16x16x32_bf16(af[2*i],   qf[0][kb0+i], sacc[0][0], 0, 0, 0);
        sacc[0][1] = __builtin_amdgcn_mfma_f32_16x16x32_bf16(af[2*i],   qf[1][kb0+i], sacc[0][1], 0, 0, 0);
        sacc[1][0] = __builtin_amdgcn_mfma_f32_16x16x32_bf16(af[2*i+1], qf[0][kb0+i], sacc[1][0], 0, 0, 0);
        sacc[1][1] = __builtin_amdgcn_mfma_f32_16x16x32_bf16(af[2*i+1], qf[1][kb0+i], sacc[1][1], 0, 0, 0);
      }
      __builtin_amdgcn_s_setprio(0);
    };
    auto gemm1_region = [&](int buf) {
#pragma unroll
      for (int nt = 0; nt < 2; ++nt)
#pragma unroll
        for (int qt = 0; qt < 2; ++qt) sacc[nt][qt] = (floatx4){0.f, 0.f, 0.f, 0.f};
      short8 afA[8], afB[8];
      a_read8(buf, 0, afA);              // cluster i+1 reads issued before
      a_read8(buf, 4, afB);              // cluster i's MFMAs (depth-2)
      g1c(afA, 0);
      a_read8(buf, 8, afA);
      g1c(afB, 4);
      a_read8(buf, 12, afB);
      g1c(afA, 8);
      g1c(afB, 12);
    };
    auto exp_pw = [&](int buf) {
#pragma unroll
      for (int qt = 0; qt < 2; ++qt)
#pragma unroll
        for (int nt = 0; nt < 2; ++nt) {
          const floatx4 s = sacc[nt][qt];
          uint2v w;
          w.x = pack2(__expf(BETA * (s[0] - 1.f)), __expf(BETA * (s[1] - 1.f)));
          w.y = pack2(__expf(BETA * (s[2] - 1.f)), __expf(BETA * (s[3] - 1.f)));
          *(uint2v*)&P_lds[buf][(qh*32 + qt*16 + l15) * PROW + nh*32 + nt*16 + quad*4] = w;
        }
    };

    // prologue
    stage(0, 0);
    asm volatile("s_waitcnt vmcnt(0)" ::: "memory");   // qf + stage(0) done
    asm volatile("s_barrier" ::: "memory");            // B0
    stage(1, 1);
    gemm1_region(0);                                   // chunk 0
    exp_pw(0);
    asm volatile("s_waitcnt vmcnt(0) lgkmcnt(0)" ::: "memory"); // stage(1)+P(0)
    asm volatile("s_barrier" ::: "memory");            // B1

    // steady: region r computes chunk r+1 -> P_lds[(r+1)&1], stages r+2
#pragma unroll 1
    for (int r = 0; r + 2 < CHUNKS; ++r) {
      stage(r + 2, r & 1);               // K_lds[r&1] free (chunk r read in r-1)
      gemm1_region((r + 1) & 1);
      exp_pw((r + 1) & 1);
      asm volatile("s_waitcnt vmcnt(0) lgkmcnt(0)" ::: "memory");
      asm volatile("s_barrier" ::: "memory");
    }
    // tail: region CHUNKS-2 computes chunk CHUNKS-1 (no staging)
    gemm1_region((CHUNKS - 1) & 1);
    exp_pw((CHUNKS - 1) & 1);
    asm volatile("s_waitcnt lgkmcnt(0)" ::: "memory");
    asm volatile("s_barrier" ::: "memory");
    // S-waves exit (O-waves' final region has no barrier)
  } else {
    // ================= O-consumer: GEMM2 + epilogue =======================
    const int w4 = wave - 4;               // d-slice [w4*128, +128)
    floatx4 oacc[4][8] = {};               // 64q x 128d (128 reg, AGPR-able)
    short8 ktf[2][8];                      // 64 reg
    const unsigned short* ktb = KnT + (size_t)(w4 * 128 + l15) * NK + nbase + quad * 8;

    auto ldKT = [&](short8* kt, int c, int kb2) {
#pragma unroll
      for (int td = 0; td < 8; ++td)
        kt[td] = *(const short8*)(ktb + (size_t)td * 16 * NK + c * BN + kb2 * 32);
    };
    auto pf_read = [&](int pbuf, int kb2, short8* pf) {
#pragma unroll
      for (int tr = 0; tr < 4; ++tr)
        pf[tr] = *(const short8*)&P_lds[pbuf][(tr*16 + l15) * PROW + kb2*32 + quad*8];
    };
    auto g2c = [&](const short8* pf, const short8* kt) {
      __builtin_amdgcn_s_setprio(1);
#pragma unroll
      for (int td = 0; td < 8; ++td)
#pragma unroll
        for (int tr = 0; tr < 4; ++tr)
          oacc[tr][td] = __builtin_amdgcn_mfma_f32_16x16x32_bf16(
              pf[tr], kt[td], oacc[tr][td], 0, 0, 0);
      __builtin_amdgcn_s_setprio(0);
    };

    ldKT(ktf[0], 0, 0); ldKT(ktf[1], 0, 1);   // chunk 0 ktf in flight
    asm volatile("s_barrier" ::: "memory");    // B0
    asm volatile("s_barrier" ::: "memory");    // B1 (P(0) now visible)

    // steady: region r consumes P(r) x ktf(chunk r); issues ktf(r+1)
#pragma unroll 1
    for (int r = 0; r + 2 < CHUNKS; ++r) {
      short8 pf0[4], pf1[4];
      pf_read(r & 1, 0, pf0);            // both halves issued early:
      pf_read(r & 1, 1, pf1);            // cluster-2's reads ahead of cluster-1
      g2c(pf0, ktf[0]);                  // (compiler waits vmcnt for ktf[0])
      ldKT(ktf[0], r + 1, 0);            // refill after last use (in-order WAR)
      g2c(pf1, ktf[1]);
      ldKT(ktf[1], r + 1, 1);
      asm volatile("s_barrier" ::: "memory");   // no waits: ktf stays in flight
    }
    // region CHUNKS-2: consume P(CHUNKS-2), issue ktf(CHUNKS-1)
    {
      const int r = CHUNKS - 2;
      short8 pf0[4], pf1[4];
      pf_read(r & 1, 0, pf0);
      pf_read(r & 1, 1, pf1);
      g2c(pf0, ktf[0]);
      ldKT(ktf[0], CHUNKS - 1, 0);
      g2c(pf1, ktf[1]);
      ldKT(ktf[1], CHUNKS - 1, 1);
      asm volatile("s_barrier" ::: "memory");
    }
    // final region: consume P(CHUNKS-1); no barrier
    {
      short8 pf0[4], pf1[4];
      pf_read((CHUNKS - 1) & 1, 0, pf0);
      pf_read((CHUNKS - 1) & 1, 1, pf1);
      g2c(pf0, ktf[0]);
      g2c(pf1, ktf[1]);
    }

    // ---- epilogue: out += ALPHA * O (out pre-init to Q) ----
    const int colbase = w4 * 128 + l15;
#pragma unroll
    for (int tr = 0; tr < 4; ++tr)
#pragma unroll
      for (int td = 0; td < 8; ++td)
#pragma unroll
        for (int r4 = 0; r4 < 4; ++r4)
          atomicAdd(out + (size_t)(q0 + tr*16 + quad*4 + r4) * D + colbase + td*16,
                    ALPHA * oacc[tr][td][r4]);
  }
}

extern "C" void kernel_launch(void* const* d_in, const int* in_sizes, int n_in,
                              void* d_out, int out_size, void* d_ws, size_t ws_size,
                              hipStream_t stream) {
  (void)in_sizes; (void)n_in; (void)out_size; (void)ws_size;
  const float* q = (const float*)d_in[0];
  const float* k = (const float*)d_in[1];
  float* out = (float*)d_out;
  unsigned short* Qn  = (unsigned short*)d_ws;          //  4 MB
  unsigned short* Kn  = Qn + (size_t)NB * D;            // 16 MB
  unsigned short* KnT = Kn + (size_t)NK * D;            // 16 MB  (total 36 MB)

  hipLaunchKernelGGL(norm_q_kernel, dim3(NB / 4),  dim3(256),  0, stream, q, out, Qn);
  hipLaunchKernelGGL(norm_k_kernel, dim3(NK / 64), dim3(1024), 0, stream, k, Kn, KnT);
  hipLaunchKernelGGL(fused_kernel, dim3((NB / BQ) * NSPLIT), dim3(512), 0, stream,
                     Qn, Kn, KnT, out);
}